// Round 3
// baseline (261.877 us; speedup 1.0000x reference)
//
#include <hip/hip_runtime.h>
#include <hip/hip_bf16.h>

#define B_ 16
#define P_ 1024
#define T_ (B_*P_)
#define CH_ 32          // chunks per batch for the softmax scan
#define CL_ (P_/CH_)    // 32 positions per chunk

// ---- ws layout (floats). Token intermediates only; weights read raw per-block. ----
// (Low region retained for layout stability; no longer written.)
constexpr int OFF_A     = 16;
constexpr int OFF_WPSI1 = 400;
constexpr int OFF_BPSI1 = OFF_WPSI1 + 1984;
constexpr int OFF_WPSI2 = OFF_BPSI1 + 64;
constexpr int OFF_BPSI2 = OFF_WPSI2 + 4096;
constexpr int OFF_WPHI1 = OFF_BPSI2 + 64;
constexpr int OFF_BPHI1 = OFF_WPHI1 + 992;
constexpr int OFF_WPHI2 = OFF_BPHI1 + 32;
constexpr int OFF_BPHI2 = OFF_WPHI2 + 1024;
constexpr int OFF_WRHO1 = OFF_BPHI2 + 32;
constexpr int OFF_BRHO1 = OFF_WRHO1 + 8192;
constexpr int OFF_WRHO2 = OFF_BRHO1 + 64;
constexpr int OFF_BRHO2 = OFF_WRHO2 + 4096;
constexpr int OFF_PHI   = OFF_BRHO2 + 64;           // T*32  phi*mask
constexpr int OFF_Z     = OFF_PHI   + T_*32;        // T*4   z = (psi*m).A2
constexpr int OFF_PREX  = OFF_Z     + T_*4;         // T*4
constexpr int OFF_EXPW  = OFF_PREX  + T_*4;         // T*4   e = exp(pre - M[b,h])
constexpr int OFF_CE    = OFF_EXPW  + T_*4;         // B*CH*4 chunk E-sums
constexpr int OFF_CS    = OFF_CE    + 2048;         // B*CH*128 chunk S-sums

static __device__ __forceinline__ bool detect_f32(const void* mask_raw) {
  return ((*(const unsigned*)mask_raw) & 0xFFFFu) == 0u;
}
static __device__ __forceinline__ float ld_any(const void* src, int i, bool isf32) {
  if (isf32) return ((const float*)src)[i];
  return __bfloat162float(((const __hip_bfloat16*)src)[i]);
}

// ---------- K1: wave-per-token MLPs. 4 tokens/block, lane=channel. ----------
// Weights staged raw->f32 into LDS per block; A = (Wkey.query)/sqrt(dp) folded
// per block (50 MFLOP total across grid — noise). Replaces the old s01 launch.
__global__ __launch_bounds__(256) void k1_token(float* __restrict__ ws,
    const int* __restrict__ measp, const void* __restrict__ times,
    const void* __restrict__ values, const void* __restrict__ mask,
    const void* __restrict__ Wpsi1, const void* __restrict__ bpsi1,
    const void* __restrict__ Wpsi2, const void* __restrict__ bpsi2,
    const void* __restrict__ Wkey,  const void* __restrict__ bkey,
    const void* __restrict__ query,
    const void* __restrict__ Wphi1, const void* __restrict__ bphi1,
    const void* __restrict__ Wphi2, const void* __restrict__ bphi2) {
  __shared__ float sWpsi1[1984], sBpsi1[64], sWpsi2[4096], sBpsi2[64];
  __shared__ float sWphi1[992],  sBphi1[32], sWphi2[1024], sBphi2[32];
  __shared__ float sA[384];      // A[j][h] at j*4+h; c0[h] at 380+h
  __shared__ float sA2T[256];    // A2T[h][jj] = A[31+jj][h]  (conflict-free z reads)
  __shared__ float sh1[4][64], sg1[4][32];
  const bool isf32 = detect_f32(mask);
  const int tid = threadIdx.x;

  // ---- stage weights ----
  for (int i = tid; i < 1984; i += 256) sWpsi1[i] = ld_any(Wpsi1, i, isf32);
  for (int i = tid; i < 4096; i += 256) sWpsi2[i] = ld_any(Wpsi2, i, isf32);
  for (int i = tid; i < 992;  i += 256) sWphi1[i] = ld_any(Wphi1, i, isf32);
  for (int i = tid; i < 1024; i += 256) sWphi2[i] = ld_any(Wphi2, i, isf32);
  if      (tid < 64)  sBpsi1[tid]       = ld_any(bpsi1, tid,       isf32);
  else if (tid < 128) sBpsi2[tid - 64]  = ld_any(bpsi2, tid - 64,  isf32);
  else if (tid < 160) sBphi1[tid - 128] = ld_any(bphi1, tid - 128, isf32);
  else if (tid < 192) sBphi2[tid - 160] = ld_any(bphi2, tid - 160, isf32);

  // ---- fold A = Wkey . query (and bias row) ----
  for (int g = tid; g < 384; g += 256) {
    const int h = g & 3, jj = g >> 2;  // jj==95 -> bias row
    float s = 0.f;
    if (jj < 95) {
      for (int d = 0; d < 32; ++d)
        s += ld_any(Wkey, jj * 128 + h * 32 + d, isf32) * ld_any(query, h * 32 + d, isf32);
    } else {
      for (int d = 0; d < 32; ++d)
        s += ld_any(bkey, h * 32 + d, isf32) * ld_any(query, h * 32 + d, isf32);
    }
    s *= 0.17677669529663687f;  // 1/sqrt(32)
    sA[g] = s;
    if (jj >= 31 && jj < 95) sA2T[h * 64 + (jj - 31)] = s;
  }
  __syncthreads();

  const int wv = __builtin_amdgcn_readfirstlane(tid >> 6);
  const int j  = tid & 63;
  const int t  = blockIdx.x * 4 + wv;

  const float tval = ld_any(times, t, isf32);
  const float vval = ld_any(values, t, isf32);
  const float mval = ld_any(mask, t, isf32);
  const int   meas = measp[t];
  const float sel  = (meas > 0) ? 1.f : 0.f;
  const int   mrow = (meas > 0) ? (8 + meas) : 0;

  float x[9];
  const float posv[4] = {1.f, 10.f, 100.f, 1000.f};
  #pragma unroll
  for (int k = 0; k < 4; ++k) {
    float s, c;
    __sincosf(tval / posv[k], &s, &c);
    x[2*k] = s; x[2*k+1] = c;
  }
  x[8] = vval;

  // psi L1, channel j
  float h1 = sBpsi1[j];
  #pragma unroll
  for (int i = 0; i < 9; ++i) h1 = fmaf(x[i], sWpsi1[i * 64 + j], h1);
  h1 = fmaf(sel, sWpsi1[mrow * 64 + j], h1);
  sh1[wv][j] = fmaxf(h1, 0.f);

  // phi L1, lanes 0..31
  if (j < 32) {
    float g1 = sBphi1[j];
    #pragma unroll
    for (int i = 0; i < 9; ++i) g1 = fmaf(x[i], sWphi1[i * 32 + j], g1);
    g1 = fmaf(sel, sWphi1[mrow * 32 + j], g1);
    sg1[wv][j] = fmaxf(g1, 0.f);
  }
  __syncthreads();

  // psi L2
  float h2 = sBpsi2[j];
  #pragma unroll 8
  for (int i = 0; i < 64; ++i) h2 = fmaf(sh1[wv][i], sWpsi2[i * 64 + j], h2);
  const float q = fmaxf(h2, 0.f) * mval;

  // z[h] = sum_j q_j * A2[j][h] — butterfly over the wave (conflict-free A2T reads)
  float z0 = q * sA2T[0 * 64 + j], z1 = q * sA2T[1 * 64 + j];
  float z2 = q * sA2T[2 * 64 + j], z3 = q * sA2T[3 * 64 + j];
  #pragma unroll
  for (int off = 32; off; off >>= 1) {
    z0 += __shfl_xor(z0, off, 64);
    z1 += __shfl_xor(z1, off, 64);
    z2 += __shfl_xor(z2, off, 64);
    z3 += __shfl_xor(z3, off, 64);
  }
  if (j == 0) {
    float* zo = ws + OFF_Z + (size_t)t * 4;
    zo[0] = z0; zo[1] = z1; zo[2] = z2; zo[3] = z3;
  }

  // phi L2 on lanes 0..31; pre_x on lanes 32..35
  if (j < 32) {
    float g2 = sBphi2[j];
    #pragma unroll 8
    for (int i = 0; i < 32; ++i) g2 = fmaf(sg1[wv][i], sWphi2[i * 32 + j], g2);
    ws[OFF_PHI + (size_t)t * 32 + j] = fmaxf(g2, 0.f) * mval;
  } else if (j < 36) {
    const int h = j - 32;
    float pr = sA[380 + h];
    #pragma unroll
    for (int i = 0; i < 9; ++i) pr = fmaf(x[i], sA[i * 4 + h], pr);
    pr = fmaf(sel, sA[mrow * 4 + h], pr);
    ws[OFF_PREX + (size_t)t * 4 + h] = pr;
  }
}

// ---------- K2: scan (cnt, z[4]) -> pre; batch-max per head; e = exp(pre-M) ----------
__global__ __launch_bounds__(256) void k2_scanz(float* __restrict__ ws,
                                                const void* __restrict__ mask) {
  const int b    = blockIdx.x;
  const int tid  = threadIdx.x;
  const int lane = tid & 63;
  const int wv   = tid >> 6;
  const bool isf32 = detect_f32(mask);
  __shared__ float swt[4][5];   // per-wave scan totals (c, z0..z3)
  __shared__ float smx[4][4];   // per-wave per-head maxima

  const float* zB = ws + OFF_Z + (size_t)b * P_ * 4;
  const int p0 = tid * 4;

  float lc[4], l0[4], l1[4], l2[4], l3[4];
  float c = 0.f, z0 = 0.f, z1 = 0.f, z2 = 0.f, z3 = 0.f;
  const float4* z4 = (const float4*)(zB + (size_t)p0 * 4);
  #pragma unroll
  for (int i = 0; i < 4; ++i) {
    const float4 zv = z4[i];
    c  += ld_any(mask, b * P_ + p0 + i, isf32);
    z0 += zv.x; z1 += zv.y; z2 += zv.z; z3 += zv.w;
    lc[i] = c; l0[i] = z0; l1[i] = z1; l2[i] = z2; l3[i] = z3;
  }

  float rc = c, r0 = z0, r1 = z1, r2 = z2, r3 = z3;
  #pragma unroll
  for (int off = 1; off < 64; off <<= 1) {
    const float uc = __shfl_up(rc, off, 64);
    const float u0 = __shfl_up(r0, off, 64);
    const float u1 = __shfl_up(r1, off, 64);
    const float u2 = __shfl_up(r2, off, 64);
    const float u3 = __shfl_up(r3, off, 64);
    if (lane >= off) { rc += uc; r0 += u0; r1 += u1; r2 += u2; r3 += u3; }
  }
  if (lane == 63) {
    swt[wv][0] = rc; swt[wv][1] = r0; swt[wv][2] = r1; swt[wv][3] = r2; swt[wv][4] = r3;
  }
  __syncthreads();
  #pragma unroll
  for (int w2 = 0; w2 < 3; ++w2) {
    if (wv > w2) {
      rc += swt[w2][0]; r0 += swt[w2][1]; r1 += swt[w2][2];
      r2 += swt[w2][3]; r3 += swt[w2][4];
    }
  }
  const float ec = rc - c, e0 = r0 - z0, e1 = r1 - z1, e2 = r2 - z2, e3 = r3 - z3;

  const float* px = ws + OFF_PREX + (size_t)b * P_ * 4;
  const float4* px4 = (const float4*)(px + (size_t)p0 * 4);
  float pre[4][4];
  float mx0 = -1e30f, mx1 = -1e30f, mx2 = -1e30f, mx3 = -1e30f;
  #pragma unroll
  for (int i = 0; i < 4; ++i) {
    const float inv = 1.f / (ec + lc[i]);
    const float4 pv = px4[i];
    pre[i][0] = pv.x + (e0 + l0[i]) * inv;
    pre[i][1] = pv.y + (e1 + l1[i]) * inv;
    pre[i][2] = pv.z + (e2 + l2[i]) * inv;
    pre[i][3] = pv.w + (e3 + l3[i]) * inv;
    mx0 = fmaxf(mx0, pre[i][0]); mx1 = fmaxf(mx1, pre[i][1]);
    mx2 = fmaxf(mx2, pre[i][2]); mx3 = fmaxf(mx3, pre[i][3]);
  }

  #pragma unroll
  for (int off = 32; off; off >>= 1) {
    mx0 = fmaxf(mx0, __shfl_xor(mx0, off, 64));
    mx1 = fmaxf(mx1, __shfl_xor(mx1, off, 64));
    mx2 = fmaxf(mx2, __shfl_xor(mx2, off, 64));
    mx3 = fmaxf(mx3, __shfl_xor(mx3, off, 64));
  }
  if (lane == 0) { smx[wv][0] = mx0; smx[wv][1] = mx1; smx[wv][2] = mx2; smx[wv][3] = mx3; }
  __syncthreads();
  const float M0 = fmaxf(fmaxf(smx[0][0], smx[1][0]), fmaxf(smx[2][0], smx[3][0]));
  const float M1 = fmaxf(fmaxf(smx[0][1], smx[1][1]), fmaxf(smx[2][1], smx[3][1]));
  const float M2 = fmaxf(fmaxf(smx[0][2], smx[1][2]), fmaxf(smx[2][2], smx[3][2]));
  const float M3 = fmaxf(fmaxf(smx[0][3], smx[1][3]), fmaxf(smx[2][3], smx[3][3]));

  float* eB = ws + OFF_EXPW + (size_t)b * P_ * 4;
  float4* e4 = (float4*)(eB + (size_t)p0 * 4);
  #pragma unroll
  for (int i = 0; i < 4; ++i) {
    float4 ev;
    ev.x = __expf(pre[i][0] - M0);
    ev.y = __expf(pre[i][1] - M1);
    ev.z = __expf(pre[i][2] - M2);
    ev.w = __expf(pre[i][3] - M3);
    e4[i] = ev;
  }
}

// ---------- K4a: per-chunk plain sums of (e, e*phi) ----------
__global__ __launch_bounds__(128) void k4a_sums(float* __restrict__ ws) {
  const int ch = blockIdx.x, b = blockIdx.y;
  const int h = threadIdx.x >> 5, d = threadIdx.x & 31;
  const float* eB   = ws + OFF_EXPW + (size_t)b * P_ * 4;
  const float* phiB = ws + OFF_PHI  + (size_t)b * P_ * 32;

  float E = 0.f, S = 0.f;
  const int pbeg = ch * CL_;
  #pragma unroll 4
  for (int p = pbeg; p < pbeg + CL_; ++p) {
    const float e  = eB[p * 4 + h];
    const float ph = phiB[p * 32 + d];
    E += e;
    S = fmaf(e, ph, S);
  }
  const int base = (b * CH_ + ch) * 4 + h;
  if (d == 0) ws[OFF_CE + base] = E;
  ws[OFF_CS + base * 32 + d] = S;
}

// ---------- K45: prefix+replay -> agg in LDS -> rho MLP -> out ----------
// 256 threads: waves 0-1 do phase 1 (prefix+replay), waves 2-3 stage W_rho1
// from raw bf16/f32 concurrently. Phase 2/3 use all 4 waves (8 tokens each).
__global__ __launch_bounds__(256) void k45_fused(float* __restrict__ ws,
    const void* __restrict__ mask,
    const void* __restrict__ Wrho1, const void* __restrict__ brho1,
    const void* __restrict__ Wrho2, const void* __restrict__ brho2,
    void* __restrict__ out) {
  __shared__ float sW1[8192];       // 32 KB
  __shared__ float sAgg[32][128];   // 16 KB
  __shared__ float sH1[32][64];     //  8 KB
  const int ch = blockIdx.x, b = blockIdx.y;
  const int tid = threadIdx.x;
  const bool isf32 = detect_f32(mask);
  const int pbeg = ch * CL_;

  if (tid < 128) {
    const int h = tid >> 5, d = tid & 31;
    const float* eB   = ws + OFF_EXPW + (size_t)b * P_ * 4;
    const float* phiB = ws + OFF_PHI  + (size_t)b * P_ * 32;
    float E = 0.f, S = 0.f;
    for (int c2 = 0; c2 < ch; ++c2) {
      const int base2 = (b * CH_ + c2) * 4 + h;
      E += ws[OFF_CE + base2];
      S += ws[OFF_CS + base2 * 32 + d];
    }
    #pragma unroll 4
    for (int p = pbeg; p < pbeg + CL_; ++p) {
      const float e  = eB[p * 4 + h];
      const float ph = phiB[p * 32 + d];
      E += e;
      S = fmaf(e, ph, S);
      sAgg[p - pbeg][h * 32 + d] = (S / E) * ld_any(mask, b * P_ + p, isf32);
    }
  } else {
    for (int i = tid - 128; i < 8192; i += 128) sW1[i] = ld_any(Wrho1, i, isf32);
  }
  __syncthreads();

  // phase 2: rho L1, each wave owns 8 tokens
  const int j = tid & 63, qw = tid >> 6;
  const float b1 = ld_any(brho1, j, isf32);
  float acc[8];
  #pragma unroll
  for (int k = 0; k < 8; ++k) acc[k] = b1;
  for (int i4 = 0; i4 < 32; ++i4) {
    const float w0 = sW1[(i4 * 4 + 0) * 64 + j];
    const float w1 = sW1[(i4 * 4 + 1) * 64 + j];
    const float w2 = sW1[(i4 * 4 + 2) * 64 + j];
    const float w3 = sW1[(i4 * 4 + 3) * 64 + j];
    #pragma unroll
    for (int k = 0; k < 8; ++k) {
      const float4 a = *(const float4*)&sAgg[qw * 8 + k][i4 * 4];
      acc[k] = fmaf(a.w, w3, fmaf(a.z, w2, fmaf(a.y, w1, fmaf(a.x, w0, acc[k]))));
    }
  }
  #pragma unroll
  for (int k = 0; k < 8; ++k) sH1[qw * 8 + k][j] = fmaxf(acc[k], 0.f);
  __syncthreads();

  // phase 3: rho L2 (W2 direct from raw; branch hoisted out of the loop)
  const float b2 = ld_any(brho2, j, isf32);
  float o[8];
  #pragma unroll
  for (int k = 0; k < 8; ++k) o[k] = b2;
  if (isf32) {
    const float* W2 = (const float*)Wrho2;
    #pragma unroll 4
    for (int i = 0; i < 64; ++i) {
      const float w = W2[i * 64 + j];
      #pragma unroll
      for (int k = 0; k < 8; ++k) o[k] = fmaf(sH1[qw * 8 + k][i], w, o[k]);
    }
  } else {
    const __hip_bfloat16* W2 = (const __hip_bfloat16*)Wrho2;
    #pragma unroll 4
    for (int i = 0; i < 64; ++i) {
      const float w = __bfloat162float(W2[i * 64 + j]);
      #pragma unroll
      for (int k = 0; k < 8; ++k) o[k] = fmaf(sH1[qw * 8 + k][i], w, o[k]);
    }
  }

  const int t0 = b * P_ + pbeg + qw * 8;
  #pragma unroll
  for (int k = 0; k < 8; ++k) {
    const float mv = ld_any(mask, t0 + k, isf32);
    const float v  = fmaxf(o[k], 0.f) * mv;
    if (isf32) {
      ((float*)out)[(size_t)(t0 + k) * 64 + j] = v;
    } else {
      ((__hip_bfloat16*)out)[(size_t)(t0 + k) * 64 + j] = __float2bfloat16(v);
    }
  }
}

extern "C" void kernel_launch(void* const* d_in, const int* in_sizes, int n_in,
                              void* d_out, int out_size, void* d_ws, size_t ws_size,
                              hipStream_t stream) {
  const int* meas = (const int*)d_in[2];
  const void* times = d_in[0];
  const void* values = d_in[1];
  const void* mask = d_in[3];
  float* ws = (float*)d_ws;

  k1_token<<<T_/4, 256, 0, stream>>>(ws, meas, times, values, mask,
                                     d_in[4], d_in[5], d_in[6], d_in[7],
                                     d_in[8], d_in[9], d_in[10],
                                     d_in[11], d_in[12], d_in[13], d_in[14]);
  k2_scanz<<<B_, 256, 0, stream>>>(ws, mask);
  k4a_sums<<<dim3(CH_, B_), 128, 0, stream>>>(ws);
  k45_fused<<<dim3(CH_, B_), 256, 0, stream>>>(ws, mask,
                                               d_in[15], d_in[16], d_in[17], d_in[18],
                                               d_out);
}

// Round 4
// 153.415 us; speedup vs baseline: 1.7070x; 1.7070x over previous
//
#include <hip/hip_runtime.h>
#include <hip/hip_bf16.h>

#define B_ 16
#define P_ 1024
#define T_ (B_*P_)
#define CH_ 32          // chunks per batch for the softmax scan
#define CL_ (P_/CH_)    // 32 positions per chunk

// ---- ws layout (floats). psi/phi weights staged f32; rho read raw in k45. ----
constexpr int OFF_A     = 16;                       // 95*4 + 4 = 384
constexpr int OFF_WPSI1 = 400;                      // 1984
constexpr int OFF_BPSI1 = OFF_WPSI1 + 1984;         // 64
constexpr int OFF_WPSI2 = OFF_BPSI1 + 64;           // 4096
constexpr int OFF_BPSI2 = OFF_WPSI2 + 4096;         // 64
constexpr int OFF_WPHI1 = OFF_BPSI2 + 64;           // 992
constexpr int OFF_BPHI1 = OFF_WPHI1 + 992;          // 32
constexpr int OFF_WPHI2 = OFF_BPHI1 + 32;           // 1024
constexpr int OFF_BPHI2 = OFF_WPHI2 + 1024;         // 32
constexpr int OFF_WRHO1 = OFF_BPHI2 + 32;           // (unused now)
constexpr int OFF_BRHO1 = OFF_WRHO1 + 8192;
constexpr int OFF_WRHO2 = OFF_BRHO1 + 64;
constexpr int OFF_BRHO2 = OFF_WRHO2 + 4096;
constexpr int OFF_PHI   = OFF_BRHO2 + 64;           // T*32  phi*mask
constexpr int OFF_Z     = OFF_PHI   + T_*32;        // T*4   z = (psi*m).A2
constexpr int OFF_PREX  = OFF_Z     + T_*4;         // T*4
constexpr int OFF_EXPW  = OFF_PREX  + T_*4;         // T*4   e = exp(pre - M[b,h])
constexpr int OFF_CE    = OFF_EXPW  + T_*4;         // B*CH*4 chunk E-sums
constexpr int OFF_CS    = OFF_CE    + 2048;         // B*CH*128 chunk S-sums

static __device__ __forceinline__ bool detect_f32(const void* mask_raw) {
  return ((*(const unsigned*)mask_raw) & 0xFFFFu) == 0u;
}
static __device__ __forceinline__ float ld_any(const void* src, int i, bool isf32) {
  if (isf32) return ((const float*)src)[i];
  return __bfloat162float(((const __hip_bfloat16*)src)[i]);
}

// ---------- S01: stage psi/phi weights to f32 (blocks >=2) + fold A (blocks 0..1) ----------
__global__ __launch_bounds__(256) void s01_prep(
    float* __restrict__ ws, const void* mask,
    const void* Wpsi1, const void* bpsi1, const void* Wpsi2, const void* bpsi2,
    const void* Wkey,  const void* bkey,  const void* query,
    const void* Wphi1, const void* bphi1, const void* Wphi2, const void* bphi2) {
  const bool isf32 = detect_f32(mask);
  if (blockIdx.x < 2) {
    const int gid = blockIdx.x * 256 + threadIdx.x;
    if (gid >= 384) return;
    const float inv_s = 0.17677669529663687f;
    const int h = gid & 3;
    const int j = gid >> 2;  // 0..95; 95 = bias row
    float s = 0.f;
    if (j < 95) {
      for (int d = 0; d < 32; ++d)
        s += ld_any(Wkey, j * 128 + h * 32 + d, isf32) * ld_any(query, h * 32 + d, isf32);
    } else {
      for (int d = 0; d < 32; ++d)
        s += ld_any(bkey, h * 32 + d, isf32) * ld_any(query, h * 32 + d, isf32);
    }
    ws[OFF_A + gid] = s * inv_s;  // A[j][h] at j*4+h; c0[h] at 380+h
    return;
  }
  const int g  = (blockIdx.x - 2) * 256 + threadIdx.x;
  const int gs = (gridDim.x - 2) * 256;
  auto st = [&](int off, const void* src, int n) {
    for (int i = g; i < n; i += gs) ws[off + i] = ld_any(src, i, isf32);
  };
  st(OFF_WPSI1, Wpsi1, 1984); st(OFF_BPSI1, bpsi1, 64);
  st(OFF_WPSI2, Wpsi2, 4096); st(OFF_BPSI2, bpsi2, 64);
  st(OFF_WPHI1, Wphi1, 992);  st(OFF_BPHI1, bphi1, 32);
  st(OFF_WPHI2, Wphi2, 1024); st(OFF_BPHI2, bphi2, 32);
}

// ---------- K1: wave-per-token MLPs. 4 tokens/block, lane=channel ----------
// Lean: weights read from ws (L2-hot). 1.5 KB LDS -> high occupancy.
__global__ __launch_bounds__(256) void k1_token(float* __restrict__ ws,
                                                const int* __restrict__ measp,
                                                const void* __restrict__ times,
                                                const void* __restrict__ values,
                                                const void* __restrict__ mask) {
  __shared__ float sh1[4][64];
  __shared__ float sg1[4][32];
  const bool isf32 = detect_f32(mask);
  const int tid = threadIdx.x;
  const int wv  = __builtin_amdgcn_readfirstlane(tid >> 6);
  const int j   = tid & 63;
  const int t   = blockIdx.x * 4 + wv;

  const float tval = ld_any(times, t, isf32);
  const float vval = ld_any(values, t, isf32);
  const float mval = ld_any(mask, t, isf32);
  const int   meas = measp[t];
  const float sel  = (meas > 0) ? 1.f : 0.f;
  const int   mrow = (meas > 0) ? (8 + meas) : 0;

  float x[9];
  const float posv[4] = {1.f, 10.f, 100.f, 1000.f};
  #pragma unroll
  for (int k = 0; k < 4; ++k) {
    float s, c;
    __sincosf(tval / posv[k], &s, &c);
    x[2*k] = s; x[2*k+1] = c;
  }
  x[8] = vval;

  // psi L1, channel j
  float h1 = ws[OFF_BPSI1 + j];
  #pragma unroll
  for (int i = 0; i < 9; ++i) h1 = fmaf(x[i], ws[OFF_WPSI1 + i * 64 + j], h1);
  h1 = fmaf(sel, ws[OFF_WPSI1 + mrow * 64 + j], h1);
  sh1[wv][j] = fmaxf(h1, 0.f);

  // phi L1, lanes 0..31
  if (j < 32) {
    float g1 = ws[OFF_BPHI1 + j];
    #pragma unroll
    for (int i = 0; i < 9; ++i) g1 = fmaf(x[i], ws[OFF_WPHI1 + i * 32 + j], g1);
    g1 = fmaf(sel, ws[OFF_WPHI1 + mrow * 32 + j], g1);
    sg1[wv][j] = fmaxf(g1, 0.f);
  }
  __syncthreads();

  // psi L2
  float h2 = ws[OFF_BPSI2 + j];
  #pragma unroll 8
  for (int i = 0; i < 64; ++i) h2 = fmaf(sh1[wv][i], ws[OFF_WPSI2 + i * 64 + j], h2);
  const float q = fmaxf(h2, 0.f) * mval;

  // z[h] = sum_j q_j * A2[j][h] — butterfly over the wave
  const float* a2 = ws + OFF_A + (31 + j) * 4;
  float z0 = q * a2[0], z1 = q * a2[1], z2 = q * a2[2], z3 = q * a2[3];
  #pragma unroll
  for (int off = 32; off; off >>= 1) {
    z0 += __shfl_xor(z0, off, 64);
    z1 += __shfl_xor(z1, off, 64);
    z2 += __shfl_xor(z2, off, 64);
    z3 += __shfl_xor(z3, off, 64);
  }
  if (j == 0) {
    float* zo = ws + OFF_Z + (size_t)t * 4;
    zo[0] = z0; zo[1] = z1; zo[2] = z2; zo[3] = z3;
  }

  // phi L2 on lanes 0..31; pre_x on lanes 32..35
  if (j < 32) {
    float g2 = ws[OFF_BPHI2 + j];
    #pragma unroll 8
    for (int i = 0; i < 32; ++i) g2 = fmaf(sg1[wv][i], ws[OFF_WPHI2 + i * 32 + j], g2);
    ws[OFF_PHI + (size_t)t * 32 + j] = fmaxf(g2, 0.f) * mval;
  } else if (j < 36) {
    const int h = j - 32;
    float pr = ws[OFF_A + 380 + h];
    #pragma unroll
    for (int i = 0; i < 9; ++i) pr = fmaf(x[i], ws[OFF_A + i * 4 + h], pr);
    pr = fmaf(sel, ws[OFF_A + mrow * 4 + h], pr);
    ws[OFF_PREX + (size_t)t * 4 + h] = pr;
  }
}

// ---------- K2: scan (cnt, z[4]) -> pre; batch-max per head; e = exp(pre-M) ----------
__global__ __launch_bounds__(256) void k2_scanz(float* __restrict__ ws,
                                                const void* __restrict__ mask) {
  const int b    = blockIdx.x;
  const int tid  = threadIdx.x;
  const int lane = tid & 63;
  const int wv   = tid >> 6;
  const bool isf32 = detect_f32(mask);
  __shared__ float swt[4][5];   // per-wave scan totals (c, z0..z3)
  __shared__ float smx[4][4];   // per-wave per-head maxima

  const float* zB = ws + OFF_Z + (size_t)b * P_ * 4;
  const int p0 = tid * 4;

  float lc[4], l0[4], l1[4], l2[4], l3[4];
  float c = 0.f, z0 = 0.f, z1 = 0.f, z2 = 0.f, z3 = 0.f;
  const float4* z4 = (const float4*)(zB + (size_t)p0 * 4);
  #pragma unroll
  for (int i = 0; i < 4; ++i) {
    const float4 zv = z4[i];
    c  += ld_any(mask, b * P_ + p0 + i, isf32);
    z0 += zv.x; z1 += zv.y; z2 += zv.z; z3 += zv.w;
    lc[i] = c; l0[i] = z0; l1[i] = z1; l2[i] = z2; l3[i] = z3;
  }

  float rc = c, r0 = z0, r1 = z1, r2 = z2, r3 = z3;
  #pragma unroll
  for (int off = 1; off < 64; off <<= 1) {
    const float uc = __shfl_up(rc, off, 64);
    const float u0 = __shfl_up(r0, off, 64);
    const float u1 = __shfl_up(r1, off, 64);
    const float u2 = __shfl_up(r2, off, 64);
    const float u3 = __shfl_up(r3, off, 64);
    if (lane >= off) { rc += uc; r0 += u0; r1 += u1; r2 += u2; r3 += u3; }
  }
  if (lane == 63) {
    swt[wv][0] = rc; swt[wv][1] = r0; swt[wv][2] = r1; swt[wv][3] = r2; swt[wv][4] = r3;
  }
  __syncthreads();
  #pragma unroll
  for (int w2 = 0; w2 < 3; ++w2) {
    if (wv > w2) {
      rc += swt[w2][0]; r0 += swt[w2][1]; r1 += swt[w2][2];
      r2 += swt[w2][3]; r3 += swt[w2][4];
    }
  }
  const float ec = rc - c, e0 = r0 - z0, e1 = r1 - z1, e2 = r2 - z2, e3 = r3 - z3;

  const float* px = ws + OFF_PREX + (size_t)b * P_ * 4;
  const float4* px4 = (const float4*)(px + (size_t)p0 * 4);
  float pre[4][4];
  float mx0 = -1e30f, mx1 = -1e30f, mx2 = -1e30f, mx3 = -1e30f;
  #pragma unroll
  for (int i = 0; i < 4; ++i) {
    const float inv = 1.f / (ec + lc[i]);
    const float4 pv = px4[i];
    pre[i][0] = pv.x + (e0 + l0[i]) * inv;
    pre[i][1] = pv.y + (e1 + l1[i]) * inv;
    pre[i][2] = pv.z + (e2 + l2[i]) * inv;
    pre[i][3] = pv.w + (e3 + l3[i]) * inv;
    mx0 = fmaxf(mx0, pre[i][0]); mx1 = fmaxf(mx1, pre[i][1]);
    mx2 = fmaxf(mx2, pre[i][2]); mx3 = fmaxf(mx3, pre[i][3]);
  }

  #pragma unroll
  for (int off = 32; off; off >>= 1) {
    mx0 = fmaxf(mx0, __shfl_xor(mx0, off, 64));
    mx1 = fmaxf(mx1, __shfl_xor(mx1, off, 64));
    mx2 = fmaxf(mx2, __shfl_xor(mx2, off, 64));
    mx3 = fmaxf(mx3, __shfl_xor(mx3, off, 64));
  }
  if (lane == 0) { smx[wv][0] = mx0; smx[wv][1] = mx1; smx[wv][2] = mx2; smx[wv][3] = mx3; }
  __syncthreads();
  const float M0 = fmaxf(fmaxf(smx[0][0], smx[1][0]), fmaxf(smx[2][0], smx[3][0]));
  const float M1 = fmaxf(fmaxf(smx[0][1], smx[1][1]), fmaxf(smx[2][1], smx[3][1]));
  const float M2 = fmaxf(fmaxf(smx[0][2], smx[1][2]), fmaxf(smx[2][2], smx[3][2]));
  const float M3 = fmaxf(fmaxf(smx[0][3], smx[1][3]), fmaxf(smx[2][3], smx[3][3]));

  float* eB = ws + OFF_EXPW + (size_t)b * P_ * 4;
  float4* e4 = (float4*)(eB + (size_t)p0 * 4);
  #pragma unroll
  for (int i = 0; i < 4; ++i) {
    float4 ev;
    ev.x = __expf(pre[i][0] - M0);
    ev.y = __expf(pre[i][1] - M1);
    ev.z = __expf(pre[i][2] - M2);
    ev.w = __expf(pre[i][3] - M3);
    e4[i] = ev;
  }
}

// ---------- K4a: per-chunk plain sums of (e, e*phi) ----------
__global__ __launch_bounds__(128) void k4a_sums(float* __restrict__ ws) {
  const int ch = blockIdx.x, b = blockIdx.y;
  const int h = threadIdx.x >> 5, d = threadIdx.x & 31;
  const float* eB   = ws + OFF_EXPW + (size_t)b * P_ * 4;
  const float* phiB = ws + OFF_PHI  + (size_t)b * P_ * 32;

  float E = 0.f, S = 0.f;
  const int pbeg = ch * CL_;
  #pragma unroll 4
  for (int p = pbeg; p < pbeg + CL_; ++p) {
    const float e  = eB[p * 4 + h];
    const float ph = phiB[p * 32 + d];
    E += e;
    S = fmaf(e, ph, S);
  }
  const int base = (b * CH_ + ch) * 4 + h;
  if (d == 0) ws[OFF_CE + base] = E;
  ws[OFF_CS + base * 32 + d] = S;
}

// ---------- K45: prefix+replay -> agg in LDS -> rho MLP -> out ----------
// 256 threads: waves 0-1 do phase 1 (prefix+replay), waves 2-3 stage W_rho1
// from raw bf16/f32 concurrently. Phase 2/3 use all 4 waves (8 tokens each).
__global__ __launch_bounds__(256) void k45_fused(float* __restrict__ ws,
    const void* __restrict__ mask,
    const void* __restrict__ Wrho1, const void* __restrict__ brho1,
    const void* __restrict__ Wrho2, const void* __restrict__ brho2,
    void* __restrict__ out) {
  __shared__ float sW1[8192];       // 32 KB
  __shared__ float sAgg[32][128];   // 16 KB
  __shared__ float sH1[32][64];     //  8 KB
  const int ch = blockIdx.x, b = blockIdx.y;
  const int tid = threadIdx.x;
  const bool isf32 = detect_f32(mask);
  const int pbeg = ch * CL_;

  if (tid < 128) {
    const int h = tid >> 5, d = tid & 31;
    const float* eB   = ws + OFF_EXPW + (size_t)b * P_ * 4;
    const float* phiB = ws + OFF_PHI  + (size_t)b * P_ * 32;
    float E = 0.f, S = 0.f;
    for (int c2 = 0; c2 < ch; ++c2) {
      const int base2 = (b * CH_ + c2) * 4 + h;
      E += ws[OFF_CE + base2];
      S += ws[OFF_CS + base2 * 32 + d];
    }
    #pragma unroll 4
    for (int p = pbeg; p < pbeg + CL_; ++p) {
      const float e  = eB[p * 4 + h];
      const float ph = phiB[p * 32 + d];
      E += e;
      S = fmaf(e, ph, S);
      sAgg[p - pbeg][h * 32 + d] = (S / E) * ld_any(mask, b * P_ + p, isf32);
    }
  } else {
    for (int i = tid - 128; i < 8192; i += 128) sW1[i] = ld_any(Wrho1, i, isf32);
  }
  __syncthreads();

  // phase 2: rho L1, each wave owns 8 tokens
  const int j = tid & 63, qw = tid >> 6;
  const float b1 = ld_any(brho1, j, isf32);
  float acc[8];
  #pragma unroll
  for (int k = 0; k < 8; ++k) acc[k] = b1;
  for (int i4 = 0; i4 < 32; ++i4) {
    const float w0 = sW1[(i4 * 4 + 0) * 64 + j];
    const float w1 = sW1[(i4 * 4 + 1) * 64 + j];
    const float w2 = sW1[(i4 * 4 + 2) * 64 + j];
    const float w3 = sW1[(i4 * 4 + 3) * 64 + j];
    #pragma unroll
    for (int k = 0; k < 8; ++k) {
      const float4 a = *(const float4*)&sAgg[qw * 8 + k][i4 * 4];
      acc[k] = fmaf(a.w, w3, fmaf(a.z, w2, fmaf(a.y, w1, fmaf(a.x, w0, acc[k]))));
    }
  }
  #pragma unroll
  for (int k = 0; k < 8; ++k) sH1[qw * 8 + k][j] = fmaxf(acc[k], 0.f);
  __syncthreads();

  // phase 3: rho L2 (W2 direct from raw; branch hoisted out of the loop)
  const float b2 = ld_any(brho2, j, isf32);
  float o[8];
  #pragma unroll
  for (int k = 0; k < 8; ++k) o[k] = b2;
  if (isf32) {
    const float* W2 = (const float*)Wrho2;
    #pragma unroll 4
    for (int i = 0; i < 64; ++i) {
      const float w = W2[i * 64 + j];
      #pragma unroll
      for (int k = 0; k < 8; ++k) o[k] = fmaf(sH1[qw * 8 + k][i], w, o[k]);
    }
  } else {
    const __hip_bfloat16* W2 = (const __hip_bfloat16*)Wrho2;
    #pragma unroll 4
    for (int i = 0; i < 64; ++i) {
      const float w = __bfloat162float(W2[i * 64 + j]);
      #pragma unroll
      for (int k = 0; k < 8; ++k) o[k] = fmaf(sH1[qw * 8 + k][i], w, o[k]);
    }
  }

  const int t0 = b * P_ + pbeg + qw * 8;
  #pragma unroll
  for (int k = 0; k < 8; ++k) {
    const float mv = ld_any(mask, t0 + k, isf32);
    const float v  = fmaxf(o[k], 0.f) * mv;
    if (isf32) {
      ((float*)out)[(size_t)(t0 + k) * 64 + j] = v;
    } else {
      ((__hip_bfloat16*)out)[(size_t)(t0 + k) * 64 + j] = __float2bfloat16(v);
    }
  }
}

extern "C" void kernel_launch(void* const* d_in, const int* in_sizes, int n_in,
                              void* d_out, int out_size, void* d_ws, size_t ws_size,
                              hipStream_t stream) {
  const int* meas = (const int*)d_in[2];
  const void* times = d_in[0];
  const void* values = d_in[1];
  const void* mask = d_in[3];
  float* ws = (float*)d_ws;

  s01_prep<<<10, 256, 0, stream>>>(ws, mask,
                                   d_in[4], d_in[5], d_in[6], d_in[7],
                                   d_in[8], d_in[9], d_in[10],
                                   d_in[11], d_in[12], d_in[13], d_in[14]);
  k1_token<<<T_/4, 256, 0, stream>>>(ws, meas, times, values, mask);
  k2_scanz<<<B_, 256, 0, stream>>>(ws, mask);
  k4a_sums<<<dim3(CH_, B_), 128, 0, stream>>>(ws);
  k45_fused<<<dim3(CH_, B_), 256, 0, stream>>>(ws, mask,
                                               d_in[15], d_in[16], d_in[17], d_in[18],
                                               d_out);
}